// Round 10
// baseline (4618.645 us; speedup 1.0000x reference)
//
#include <hip/hip_runtime.h>

constexpr int kB   = 32;    // batch
constexpr int kNS  = 100;   // n_support
constexpr int kNW  = 10;    // n_way
constexpr int kNZ  = 1000;  // kNS*kNW
constexpr int kD   = 512;   // feature dim
constexpr int kNQ  = 150;   // N*Q query rows
constexpr int kIt  = 15;    // IPM iterations
constexpr int kHalf = 50;
constexpr int kQrt  = 25;   // rows per quarter-strip
constexpr int kPan  = 4;    // pivots per panel (barrier amortization)

// -------------------------------------------------------------------------
// K[b][i][j] = <sup_i, sup_j>  (fp32 accumulate, stored fp64 for the IPM)
__global__ __launch_bounds__(128) void gram_kernel(const float* __restrict__ sup,
                                                   double* __restrict__ K64)
{
    const int i = blockIdx.x;
    const int b = blockIdx.y;
    const int tid = threadIdx.x;
    __shared__ float rowi[kD];
    const float* supb = sup + (size_t)b * kNS * kD;
    reinterpret_cast<float4*>(rowi)[tid] =
        reinterpret_cast<const float4*>(supb + (size_t)i * kD)[tid];
    __syncthreads();
    for (int j = tid; j < kNS; j += 128) {
        const float4* rj = reinterpret_cast<const float4*>(supb + (size_t)j * kD);
        float acc = 0.0f;
        for (int d4 = 0; d4 < kD / 4; ++d4) {
            float4 v = rj[d4];
            acc += rowi[4*d4+0]*v.x + rowi[4*d4+1]*v.y
                 + rowi[4*d4+2]*v.z + rowi[4*d4+3]*v.w;
        }
        K64[((size_t)b * kNS + i) * kNS + j] = (double)acc;
    }
}

// compat[b][i][q] = <sup_i, qry_q>
__global__ __launch_bounds__(256) void compat_kernel(const float* __restrict__ sup,
                                                     const float* __restrict__ qry,
                                                     float* __restrict__ compat)
{
    const int i = blockIdx.x;
    const int b = blockIdx.y;
    const int tid = threadIdx.x;
    __shared__ float rowi[kD];
    const float* supb = sup + (size_t)b * kNS * kD;
    const float* qryb = qry + (size_t)b * kNQ * kD;
    if (tid < 128)
        reinterpret_cast<float4*>(rowi)[tid] =
            reinterpret_cast<const float4*>(supb + (size_t)i * kD)[tid];
    __syncthreads();
    for (int j = tid; j < kNQ; j += 256) {
        const float4* rj = reinterpret_cast<const float4*>(qryb + (size_t)j * kD);
        float acc = 0.0f;
        for (int d4 = 0; d4 < kD / 4; ++d4) {
            float4 v = rj[d4];
            acc += rowi[4*d4+0]*v.x + rowi[4*d4+1]*v.y
                 + rowi[4*d4+2]*v.z + rowi[4*d4+3]*v.w;
        }
        compat[((size_t)b * kNS + i) * kNQ + j] = acc;
    }
}

__global__ __launch_bounds__(256) void init_kernel(double* __restrict__ z,
                                                   double* __restrict__ nu,
                                                   double* __restrict__ s,
                                                   double* __restrict__ lam,
                                                   double* __restrict__ mu_g)
{
    const int b = blockIdx.x;
    const int tid = threadIdx.x;
    for (int m = tid; m < kNZ; m += 256) {
        z[b*kNZ + m]   = 0.0;
        s[b*kNZ + m]   = 1.0;
        lam[b*kNZ + m] = 1.0;
    }
    if (tid < kNS) nu[b*kNS + tid] = 0.0;
    if (tid == 0)  mu_g[b] = 1.0;   // dot(s0,lam0)/kNZ
}

// -------------------------------------------------------------------------
// Panel solve: m = B^-1 rhs via 4x4 adjugate (cofactor) inverse — ONE fp64
// divide (1/det) instead of lu4's four sequential divides; sub-determinants
// are independent (high ILP, short critical path). B is an SPD principal
// block of the running Schur complement -> well-conditioned in fp64.
__device__ __forceinline__ void adj4_solve(const double B[4][4],
                                           double b0, double b1, double b2, double b3,
                                           double& m0, double& m1, double& m2, double& m3)
{
    const double s0 = B[0][0]*B[1][1] - B[1][0]*B[0][1];
    const double s1 = B[0][0]*B[1][2] - B[1][0]*B[0][2];
    const double s2 = B[0][0]*B[1][3] - B[1][0]*B[0][3];
    const double s3 = B[0][1]*B[1][2] - B[1][1]*B[0][2];
    const double s4 = B[0][1]*B[1][3] - B[1][1]*B[0][3];
    const double s5 = B[0][2]*B[1][3] - B[1][2]*B[0][3];
    const double c5 = B[2][2]*B[3][3] - B[3][2]*B[2][3];
    const double c4 = B[2][1]*B[3][3] - B[3][1]*B[2][3];
    const double c3 = B[2][1]*B[3][2] - B[3][1]*B[2][2];
    const double c2 = B[2][0]*B[3][3] - B[3][0]*B[2][3];
    const double c1 = B[2][0]*B[3][2] - B[3][0]*B[2][2];
    const double c0 = B[2][0]*B[3][1] - B[3][0]*B[2][1];
    const double det = s0*c5 - s1*c4 + s2*c3 + s3*c2 - s4*c1 + s5*c0;
    const double id = 1.0 / det;
    const double i00 = ( B[1][1]*c5 - B[1][2]*c4 + B[1][3]*c3) * id;
    const double i01 = (-B[0][1]*c5 + B[0][2]*c4 - B[0][3]*c3) * id;
    const double i02 = ( B[3][1]*s5 - B[3][2]*s4 + B[3][3]*s3) * id;
    const double i03 = (-B[2][1]*s5 + B[2][2]*s4 - B[2][3]*s3) * id;
    const double i10 = (-B[1][0]*c5 + B[1][2]*c2 - B[1][3]*c1) * id;
    const double i11 = ( B[0][0]*c5 - B[0][2]*c2 + B[0][3]*c1) * id;
    const double i12 = (-B[3][0]*s5 + B[3][2]*s2 - B[3][3]*s1) * id;
    const double i13 = ( B[2][0]*s5 - B[2][2]*s2 + B[2][3]*s1) * id;
    const double i20 = ( B[1][0]*c4 - B[1][1]*c2 + B[1][3]*c0) * id;
    const double i21 = (-B[0][0]*c4 + B[0][1]*c2 - B[0][3]*c0) * id;
    const double i22 = ( B[3][0]*s4 - B[3][1]*s2 + B[3][3]*s0) * id;
    const double i23 = (-B[2][0]*s4 + B[2][1]*s2 - B[2][3]*s0) * id;
    const double i30 = (-B[1][0]*c3 + B[1][1]*c1 - B[1][2]*c0) * id;
    const double i31 = ( B[0][0]*c3 - B[0][1]*c1 + B[0][2]*c0) * id;
    const double i32 = (-B[3][0]*s3 + B[3][1]*s1 - B[3][2]*s0) * id;
    const double i33 = ( B[2][0]*s3 - B[2][1]*s1 + B[2][2]*s0) * id;
    m0 = i00*b0 + i01*b1 + i02*b2 + i03*b3;
    m1 = i10*b0 + i11*b1 + i12*b2 + i13*b3;
    m2 = i20*b0 + i21*b1 + i22*b2 + i23*b3;
    m3 = i30*b0 + i31*b1 + i32*b2 + i33*b3;
}

// Rank-4 update of the 25 owned rows from signed panel rows in LDS.
// hreg[r] = s*hreg[r] - sum_p sig_i*W[p][i]*m[p]  (sig pre-applied in Wsg)
#define PANEL_UPDATE(SREGARR, WSG, BUF, BASE, SCL, M0, M1, M2, M3)            \
    {                                                                          \
        _Pragma("unroll")                                                      \
        for (int r = 0; r < kQrt; ++r) SREGARR[r] *= SCL;                      \
        _Pragma("unroll")                                                      \
        for (int p = 0; p < kPan; ++p) {                                       \
            const double mp = (p==0) ? M0 : (p==1) ? M1 : (p==2) ? M2 : M3;    \
            _Pragma("unroll")                                                  \
            for (int c0 = 0; c0 < 2; ++c0) {                                   \
                const int off0 = c0 ? 13 : 0;                                  \
                const int cnt  = c0 ? 12 : 13;                                 \
                double w[13];                                                  \
                _Pragma("unroll")                                              \
                for (int u = 0; u < 13; ++u)                                   \
                    if (u < cnt) w[u] = WSG[BUF][p][BASE + off0 + u];          \
                __builtin_amdgcn_sched_barrier(0);                             \
                _Pragma("unroll")                                              \
                for (int u = 0; u < 13; ++u)                                   \
                    if (u < cnt)                                               \
                        SREGARR[off0+u] = fma(-mp, w[u], SREGARR[off0+u]);     \
            }                                                                  \
        }                                                                      \
    }

// -------------------------------------------------------------------------
// One block (512 thr = 8 waves) per (b,a): (h=tid>>7, j=tid&127) owns rows
// [h*25, h*25+25) of column j of H_a = K + diag(1 + lam_a/s_a).
// Panel-blocked GJ: 4 pivots per barrier (25 barriers), block formulas
// B->B^-1, R->B^-1 R, C->-CB^-1, D->D-CB^-1R; C recovered from panel ROWS
// via the symmetric-GJ sign invariant, pre-applied in a signed LDS copy.
__global__ __launch_bounds__(512) void ipm_invert_kernel(
    const double* __restrict__ K64, const int* __restrict__ labels,
    const double* __restrict__ z, const double* __restrict__ nu,
    const double* __restrict__ s, const double* __restrict__ lam,
    const double* __restrict__ mu_g,
    double* __restrict__ Hinv, double* __restrict__ tvec)
{
    const int b = blockIdx.x / kNW;
    const int a = blockIdx.x - b * kNW;
    const int tid = threadIdx.x;
    const int h = tid >> 7;
    const int j = tid & 127;
    const bool act = (j < kNS);
    const int base = h * kQrt;

    __shared__ double za[kNS], sa[kNS], la[kNS], da[kNS], nus[kNS], r1s[kNS];
    __shared__ double part4[4][kNS];
    __shared__ alignas(16) double Wr [2][kPan][kNS + 8];  // raw panel rows
    __shared__ alignas(16) double Wsg[2][kPan][kNS + 8];  // signed panel rows
    __shared__ int labs[kNS];

    const double* zb = z   + (size_t)b * kNZ;
    const double* sb = s   + (size_t)b * kNZ;
    const double* lb = lam + (size_t)b * kNZ;
    const double* Kb = K64 + (size_t)b * kNS * kNS;

    if (tid < kNS) {
        double zv = zb[tid * kNW + a];
        double sv = sb[tid * kNW + a];
        double lv = lb[tid * kNW + a];
        za[tid] = zv; sa[tid] = sv; la[tid] = lv; da[tid] = lv / sv;
        nus[tid]  = nu[b * kNS + tid];
        labs[tid] = labels[b * kNS + tid];
    }
    __syncthreads();

    // Build H column j (own 25 rows) in registers; fused partial of (K z_a).
    double hreg[kQrt];
    if (act) {
        double kzp = 0.0;
        #pragma unroll
        for (int r = 0; r < kQrt; ++r) {
            const int i = base + r;
            double kv = Kb[(size_t)i * kNS + j];
            kzp += kv * za[i];
            hreg[r] = (i == j) ? (kv + 1.0 + da[j]) : kv;
        }
        part4[h][j] = kzp;
        if (h == 0) {   // seed panel 0 rows (0..3); sign vs k0=0 -> all +
            #pragma unroll
            for (int p = 0; p < kPan; ++p) {
                Wr [0][p][j] = hreg[p];
                Wsg[0][p][j] = hreg[p];
            }
        }
    }
    __syncthreads();
    if (tid < kNS) {
        const double mu = mu_g[b];
        const int i = tid;
        double kz = part4[0][i] + part4[1][i] + part4[2][i] + part4[3][i];
        double yv = (labs[i] == a) ? 1.0 : 0.0;
        double rd = kz + za[i] - yv + la[i] + nus[i];
        double rp = za[i] + sa[i] - 0.1 * yv;      // h = C_REG*y
        double rc = la[i] * sa[i] - 0.1 * mu;      // sigma = 0.1
        r1s[i] = -rd + (rc - la[i] * rp) / sa[i];
    }

    // Panel-blocked Gauss-Jordan inverse: 25 panels, 1 barrier each.
    #pragma unroll 1
    for (int k0 = 0; k0 < kNS; k0 += kPan) {
        const int buf = (k0 >> 2) & 1, nbuf = 1 - buf;
        __syncthreads();                     // Wr/Wsg[buf] complete
        if (act) {
            // B = panel rows x panel cols (raw, broadcast reads)
            double B[4][4];
            #pragma unroll
            for (int p = 0; p < 4; ++p)
                #pragma unroll
                for (int q = 0; q < 4; ++q)
                    B[p][q] = Wr[buf][p][k0 + q];
            // rhs: e_q for panel columns, else panel-row entries of col j
            const bool inpan = (j >= k0) && (j < k0 + kPan);
            const int  q     = j - k0;
            double b0 = inpan ? (q == 0 ? 1.0 : 0.0) : Wr[buf][0][j];
            double b1 = inpan ? (q == 1 ? 1.0 : 0.0) : Wr[buf][1][j];
            double b2 = inpan ? (q == 2 ? 1.0 : 0.0) : Wr[buf][2][j];
            double b3 = inpan ? (q == 3 ? 1.0 : 0.0) : Wr[buf][3][j];
            double m0, m1, m2, m3;
            adj4_solve(B, b0, b1, b2, b3, m0, m1, m2, m3);

            const double scl = inpan ? 0.0 : 1.0;
            PANEL_UPDATE(hreg, Wsg, buf, base, scl, m0, m1, m2, m3);

            // panel rows get m directly (overwrite generic update)
            if (k0 < base + kQrt && k0 + kPan - 1 >= base) {
                #pragma unroll
                for (int r = 0; r < kQrt; ++r) {
                    const int i = base + r;
                    if (i >= k0 && i < k0 + kPan) {
                        const int p = i - k0;
                        hreg[r] = (p==0) ? m0 : (p==1) ? m1 : (p==2) ? m2 : m3;
                    }
                }
            }
            // write-ahead next panel rows (raw + signed vs kn0)
            const int kn0 = k0 + kPan;
            if (kn0 < kNS && kn0 < base + kQrt && kn0 + kPan - 1 >= base) {
                #pragma unroll
                for (int r = 0; r < kQrt; ++r) {
                    const int i = base + r;
                    if (i >= kn0 && i < kn0 + kPan) {
                        const int p = i - kn0;
                        Wr [nbuf][p][j] = hreg[r];
                        Wsg[nbuf][p][j] = (j < kn0) ? -hreg[r] : hreg[r];
                    }
                }
            }
        }
    }

    // Write Hinv (coalesced) + t_a = Hinv * r1 (4-way combine via symmetry)
    double* Hb = Hinv + (size_t)(b * kNW + a) * kNS * kNS;
    if (act) {
        double tp = 0.0;
        #pragma unroll
        for (int r = 0; r < kQrt; ++r) {
            Hb[(size_t)(base + r) * kNS + j] = hreg[r];
            tp += hreg[r] * r1s[base + r];
        }
        part4[h][j] = tp;
    }
    __syncthreads();
    if (tid < kNS)
        tvec[(size_t)(b * kNW + a) * kNS + tid] =
            part4[0][tid] + part4[1][tid] + part4[2][tid] + part4[3][tid];
}

// -------------------------------------------------------------------------
// S[b] = sum_a Hinv_a[b] — full-GPU streaming reduction (320 blocks).
__global__ __launch_bounds__(256) void sbuild_kernel(const double* __restrict__ Hinv,
                                                     double* __restrict__ Sg)
{
    const int b  = blockIdx.x / kNW;
    const int rc = blockIdx.x - b * kNW;
    const int tid = threadIdx.x;
    const double* Hb = Hinv + (size_t)b * kNW * kNS * kNS;
    for (int e = tid; e < kNS * kNS / kNW; e += 256) {
        const int idx = rc * (kNS * kNS / kNW) + e;
        double acc = 0.0;
        #pragma unroll
        for (int a = 0; a < kNW; ++a) acc += Hb[(size_t)a * kNS * kNS + idx];
        Sg[(size_t)b * kNS * kNS + idx] = acc;
    }
}

// -------------------------------------------------------------------------
// One block (512 thr) per b: panel-blocked GJ solve S dnu = sum_a t_a + rp2.
// rhs is column 100 (j==100 threads; never a pivot column).
__global__ __launch_bounds__(512) void schur_solve_kernel(
    const double* __restrict__ Sg, const double* __restrict__ tvec,
    const double* __restrict__ z, double* __restrict__ dnu_g)
{
    const int b = blockIdx.x;
    const int tid = threadIdx.x;
    const int h = tid >> 7;
    const int j = tid & 127;
    const int base = h * kQrt;
    const bool act  = (j < kNS);
    const bool actS = (j <= kNS);

    __shared__ double rhs[kNS];
    __shared__ alignas(16) double Wr [2][kPan][kNS + 8];
    __shared__ alignas(16) double Wsg[2][kPan][kNS + 8];

    const double* Sb = Sg   + (size_t)b * kNS * kNS;
    const double* tb = tvec + (size_t)b * kNW * kNS;
    const double* zb = z    + (size_t)b * kNZ;

    if (tid < kNS) {
        double acc = 0.0, rp2 = 0.0;
        #pragma unroll
        for (int a = 0; a < kNW; ++a) {
            acc += tb[a * kNS + tid];
            rp2 += zb[tid * kNW + a];
        }
        rhs[tid] = acc + rp2;
    }
    __syncthreads();

    double sreg[kQrt];
    if (act) {
        #pragma unroll
        for (int r = 0; r < kQrt; ++r)
            sreg[r] = Sb[(size_t)(base + r) * kNS + j];
    } else if (j == kNS) {
        #pragma unroll
        for (int r = 0; r < kQrt; ++r) sreg[r] = rhs[base + r];
    }
    if (actS && h == 0) {
        #pragma unroll
        for (int p = 0; p < kPan; ++p) {
            Wr [0][p][j] = sreg[p];
            Wsg[0][p][j] = sreg[p];
        }
    }

    #pragma unroll 1
    for (int k0 = 0; k0 < kNS; k0 += kPan) {
        const int buf = (k0 >> 2) & 1, nbuf = 1 - buf;
        __syncthreads();
        if (actS) {
            double B[4][4];
            #pragma unroll
            for (int p = 0; p < 4; ++p)
                #pragma unroll
                for (int q = 0; q < 4; ++q)
                    B[p][q] = Wr[buf][p][k0 + q];
            const bool inpan = (j >= k0) && (j < k0 + kPan);  // j==100 never
            const int  q     = j - k0;
            double b0 = inpan ? (q == 0 ? 1.0 : 0.0) : Wr[buf][0][j];
            double b1 = inpan ? (q == 1 ? 1.0 : 0.0) : Wr[buf][1][j];
            double b2 = inpan ? (q == 2 ? 1.0 : 0.0) : Wr[buf][2][j];
            double b3 = inpan ? (q == 3 ? 1.0 : 0.0) : Wr[buf][3][j];
            double m0, m1, m2, m3;
            adj4_solve(B, b0, b1, b2, b3, m0, m1, m2, m3);

            const double scl = inpan ? 0.0 : 1.0;
            PANEL_UPDATE(sreg, Wsg, buf, base, scl, m0, m1, m2, m3);

            if (k0 < base + kQrt && k0 + kPan - 1 >= base) {
                #pragma unroll
                for (int r = 0; r < kQrt; ++r) {
                    const int i = base + r;
                    if (i >= k0 && i < k0 + kPan) {
                        const int p = i - k0;
                        sreg[r] = (p==0) ? m0 : (p==1) ? m1 : (p==2) ? m2 : m3;
                    }
                }
            }
            const int kn0 = k0 + kPan;
            if (kn0 < kNS && kn0 < base + kQrt && kn0 + kPan - 1 >= base) {
                #pragma unroll
                for (int r = 0; r < kQrt; ++r) {
                    const int i = base + r;
                    if (i >= kn0 && i < kn0 + kPan) {
                        const int p = i - kn0;
                        Wr [nbuf][p][j] = sreg[r];
                        Wsg[nbuf][p][j] = (j < kn0) ? -sreg[r] : sreg[r];
                    }
                }
            }
        }
    }

    if (j == kNS) {
        #pragma unroll
        for (int r = 0; r < kQrt; ++r)
            dnu_g[(size_t)b * kNS + base + r] = sreg[r];
    }
}

// -------------------------------------------------------------------------
// One block per (b,a): dz_a = t_a - Hinv_a*dnu (full-GPU streaming of Hinv),
// ds/dlam, per-block min step-ratio.
__global__ __launch_bounds__(256) void dz_kernel(
    const int* __restrict__ labels,
    const double* __restrict__ Hinv, const double* __restrict__ tvec,
    const double* __restrict__ dnu_g,
    const double* __restrict__ z, const double* __restrict__ s,
    const double* __restrict__ lam, const double* __restrict__ mu_g,
    double* __restrict__ dz_g, double* __restrict__ ds_g,
    double* __restrict__ dl_g, double* __restrict__ minr_g)
{
    const int b = blockIdx.x / kNW;
    const int a = blockIdx.x - b * kNW;
    const int tid = threadIdx.x;
    const int h = tid >> 7;
    const int j = tid & 127;

    __shared__ double dnus[kNS];
    __shared__ double p2[2][kNS];
    __shared__ double red[256];

    const double* Hb = Hinv + (size_t)(b * kNW + a) * kNS * kNS;

    if (tid < kNS) dnus[tid] = dnu_g[(size_t)b * kNS + tid];
    __syncthreads();

    if (j < kNS) {
        double p = 0.0;
        #pragma unroll
        for (int r = 0; r < kHalf; ++r)
            p += Hb[(size_t)(h * kHalf + r) * kNS + j] * dnus[h * kHalf + r];
        p2[h][j] = p;
    }
    __syncthreads();

    double lmin = 1e300;
    if (tid < kNS) {
        const int i = tid;
        const size_t m = (size_t)b * kNZ + i * kNW + a;
        const double mu = mu_g[b];
        double dz = tvec[(size_t)(b * kNW + a) * kNS + i] - (p2[0][i] + p2[1][i]);
        double yv = (labels[b * kNS + i] == a) ? 1.0 : 0.0;
        double zv = z[m], sv = s[m], lv = lam[m];
        double rp = zv + sv - 0.1 * yv;
        double rc = lv * sv - 0.1 * mu;
        double ds = -rp - dz;
        double dl = (-rc - lv * ds) / sv;
        dz_g[m] = dz; ds_g[m] = ds; dl_g[m] = dl;
        if (ds < 0.0) lmin = fmin(lmin, -sv / ds);
        if (dl < 0.0) lmin = fmin(lmin, -lv / dl);
    }
    red[tid] = lmin; __syncthreads();
    for (int off = 128; off > 0; off >>= 1) {
        if (tid < off) red[tid] = fmin(red[tid], red[tid + off]);
        __syncthreads();
    }
    if (tid == 0) minr_g[b * kNW + a] = red[0];
}

// -------------------------------------------------------------------------
// One block per b: alpha from the 10 per-class mins, state update, next mu.
__global__ __launch_bounds__(256) void update_kernel(
    const double* __restrict__ minr_g, const double* __restrict__ dnu_g,
    const double* __restrict__ dz_g, const double* __restrict__ ds_g,
    const double* __restrict__ dl_g,
    double* __restrict__ z, double* __restrict__ nu,
    double* __restrict__ s, double* __restrict__ lam,
    double* __restrict__ mu_g)
{
    const int b = blockIdx.x;
    const int tid = threadIdx.x;
    __shared__ double red[256];

    double am = 1e300;
    #pragma unroll
    for (int a = 0; a < kNW; ++a) am = fmin(am, minr_g[b * kNW + a]);
    const double alpha = fmin(1.0, 0.99 * am);

    double* zb = z   + (size_t)b * kNZ;
    double* sb = s   + (size_t)b * kNZ;
    double* lb = lam + (size_t)b * kNZ;

    double md = 0.0;
    #pragma unroll
    for (int tcl = 0; tcl < 4; ++tcl) {
        const int  e = tid + tcl * 256;
        const size_t m = (size_t)b * kNZ + e;
        if (e < kNZ) {
            double zn = zb[e] + alpha * dz_g[m];
            double sn = sb[e] + alpha * ds_g[m];
            double ln = lb[e] + alpha * dl_g[m];
            zb[e] = zn; sb[e] = sn; lb[e] = ln;
            md += sn * ln;
        }
    }
    red[tid] = md; __syncthreads();
    for (int off = 128; off > 0; off >>= 1) {
        if (tid < off) red[tid] += red[tid + off];
        __syncthreads();
    }
    if (tid == 0) mu_g[b] = red[0] / kNZ;
    if (tid < kNS) nu[(size_t)b * kNS + tid] += alpha * dnu_g[(size_t)b * kNS + tid];
}

// -------------------------------------------------------------------------
// logits[b][q][n] = sum_s compat[b][s][q] * z[b][s*10+n]
__global__ __launch_bounds__(256) void logits_kernel(const float* __restrict__ compat,
                                                     const double* __restrict__ z,
                                                     float* __restrict__ out)
{
    const int b = blockIdx.x;
    const int tid = threadIdx.x;
    const float* cb = compat + (size_t)b * kNS * kNQ;
    const double* zb = z + (size_t)b * kNZ;
    __shared__ double zs[kNZ];
    for (int m = tid; m < kNZ; m += 256) zs[m] = zb[m];
    __syncthreads();
    for (int idx = tid; idx < kNQ * kNW; idx += 256) {
        int q = idx / kNW, n = idx - q * kNW;
        double acc = 0.0;
        for (int s2 = 0; s2 < kNS; ++s2)
            acc += (double)cb[(size_t)s2 * kNQ + q] * zs[s2 * kNW + n];
        out[(size_t)b * kNQ * kNW + idx] = (float)acc;
    }
}

// -------------------------------------------------------------------------
extern "C" void kernel_launch(void* const* d_in, const int* in_sizes, int n_in,
                              void* d_out, int out_size, void* d_ws, size_t ws_size,
                              hipStream_t stream)
{
    const float* sup    = (const float*)d_in[0];   // (32,10,10,512)
    const int*   labels = (const int*)  d_in[1];   // (32,10,10)
    const float* qry    = (const float*)d_in[2];   // (32,10,15,512)
    float* out = (float*)d_out;                    // (32,150,10) fp32

    char* ws = (char*)d_ws;
    size_t off = 0;
    auto alloc = [&](size_t bytes) -> void* {
        void* p = ws + off;
        off += (bytes + 255) & ~(size_t)255;
        return p;
    };
    double* K64    = (double*)alloc(sizeof(double) * kB * kNS * kNS);        // 2.56 MB
    double* z      = (double*)alloc(sizeof(double) * kB * kNZ);
    double* nu     = (double*)alloc(sizeof(double) * kB * kNS);
    double* s      = (double*)alloc(sizeof(double) * kB * kNZ);
    double* lam    = (double*)alloc(sizeof(double) * kB * kNZ);
    double* mu_g   = (double*)alloc(sizeof(double) * kB);
    double* Hinv   = (double*)alloc(sizeof(double) * kB * kNW * kNS * kNS);  // 25.6 MB
    double* Sg     = (double*)alloc(sizeof(double) * kB * kNS * kNS);        // 2.56 MB
    double* tvec   = (double*)alloc(sizeof(double) * kB * kNW * kNS);
    double* dnu_g  = (double*)alloc(sizeof(double) * kB * kNS);
    double* dz_g   = (double*)alloc(sizeof(double) * kB * kNZ);
    double* ds_g   = (double*)alloc(sizeof(double) * kB * kNZ);
    double* dl_g   = (double*)alloc(sizeof(double) * kB * kNZ);
    double* minr_g = (double*)alloc(sizeof(double) * kB * kNW);
    float*  compat = (float*) alloc(sizeof(float)  * kB * kNS * kNQ);        // 1.92 MB

    gram_kernel  <<<dim3(kNS, kB), 128, 0, stream>>>(sup, K64);
    compat_kernel<<<dim3(kNS, kB), 256, 0, stream>>>(sup, qry, compat);
    init_kernel  <<<kB, 256, 0, stream>>>(z, nu, s, lam, mu_g);

    for (int it = 0; it < kIt; ++it) {
        ipm_invert_kernel<<<kB * kNW, 512, 0, stream>>>(K64, labels, z, nu, s,
                                                        lam, mu_g, Hinv, tvec);
        sbuild_kernel<<<kB * kNW, 256, 0, stream>>>(Hinv, Sg);
        schur_solve_kernel<<<kB, 512, 0, stream>>>(Sg, tvec, z, dnu_g);
        dz_kernel<<<kB * kNW, 256, 0, stream>>>(labels, Hinv, tvec, dnu_g,
                                                z, s, lam, mu_g,
                                                dz_g, ds_g, dl_g, minr_g);
        update_kernel<<<kB, 256, 0, stream>>>(minr_g, dnu_g, dz_g, ds_g, dl_g,
                                              z, nu, s, lam, mu_g);
    }

    logits_kernel<<<kB, 256, 0, stream>>>(compat, z, out);
}

// Round 11
// 4521.952 us; speedup vs baseline: 1.0214x; 1.0214x over previous
//
#include <hip/hip_runtime.h>

constexpr int kB   = 32;    // batch
constexpr int kNS  = 100;   // n_support
constexpr int kNW  = 10;    // n_way
constexpr int kNZ  = 1000;  // kNS*kNW
constexpr int kD   = 512;   // feature dim
constexpr int kNQ  = 150;   // N*Q query rows
constexpr int kIt  = 15;    // IPM iterations
constexpr int kHalf = 50;
constexpr int kQrt  = 25;   // rows per quarter-strip
constexpr int kPan  = 4;    // pivots per panel (barrier amortization)

// -------------------------------------------------------------------------
// K[b][i][j] = <sup_i, sup_j>  (fp32 accumulate, stored fp64 for the IPM)
__global__ __launch_bounds__(128) void gram_kernel(const float* __restrict__ sup,
                                                   double* __restrict__ K64)
{
    const int i = blockIdx.x;
    const int b = blockIdx.y;
    const int tid = threadIdx.x;
    __shared__ float rowi[kD];
    const float* supb = sup + (size_t)b * kNS * kD;
    reinterpret_cast<float4*>(rowi)[tid] =
        reinterpret_cast<const float4*>(supb + (size_t)i * kD)[tid];
    __syncthreads();
    for (int j = tid; j < kNS; j += 128) {
        const float4* rj = reinterpret_cast<const float4*>(supb + (size_t)j * kD);
        float acc = 0.0f;
        for (int d4 = 0; d4 < kD / 4; ++d4) {
            float4 v = rj[d4];
            acc += rowi[4*d4+0]*v.x + rowi[4*d4+1]*v.y
                 + rowi[4*d4+2]*v.z + rowi[4*d4+3]*v.w;
        }
        K64[((size_t)b * kNS + i) * kNS + j] = (double)acc;
    }
}

// compat[b][i][q] = <sup_i, qry_q>
__global__ __launch_bounds__(256) void compat_kernel(const float* __restrict__ sup,
                                                     const float* __restrict__ qry,
                                                     float* __restrict__ compat)
{
    const int i = blockIdx.x;
    const int b = blockIdx.y;
    const int tid = threadIdx.x;
    __shared__ float rowi[kD];
    const float* supb = sup + (size_t)b * kNS * kD;
    const float* qryb = qry + (size_t)b * kNQ * kD;
    if (tid < 128)
        reinterpret_cast<float4*>(rowi)[tid] =
            reinterpret_cast<const float4*>(supb + (size_t)i * kD)[tid];
    __syncthreads();
    for (int j = tid; j < kNQ; j += 256) {
        const float4* rj = reinterpret_cast<const float4*>(qryb + (size_t)j * kD);
        float acc = 0.0f;
        for (int d4 = 0; d4 < kD / 4; ++d4) {
            float4 v = rj[d4];
            acc += rowi[4*d4+0]*v.x + rowi[4*d4+1]*v.y
                 + rowi[4*d4+2]*v.z + rowi[4*d4+3]*v.w;
        }
        compat[((size_t)b * kNS + i) * kNQ + j] = acc;
    }
}

__global__ __launch_bounds__(256) void init_kernel(double* __restrict__ z,
                                                   double* __restrict__ nu,
                                                   double* __restrict__ s,
                                                   double* __restrict__ lam,
                                                   double* __restrict__ mu_g)
{
    const int b = blockIdx.x;
    const int tid = threadIdx.x;
    for (int m = tid; m < kNZ; m += 256) {
        z[b*kNZ + m]   = 0.0;
        s[b*kNZ + m]   = 1.0;
        lam[b*kNZ + m] = 1.0;
    }
    if (tid < kNS) nu[b*kNS + tid] = 0.0;
    if (tid == 0)  mu_g[b] = 1.0;   // dot(s0,lam0)/kNZ
}

// -------------------------------------------------------------------------
// 4x4 adjugate inverse (one fp64 divide, high ILP).
__device__ __forceinline__ void adj4_inv(const double B[4][4], double I4[4][4])
{
    const double s0 = B[0][0]*B[1][1] - B[1][0]*B[0][1];
    const double s1 = B[0][0]*B[1][2] - B[1][0]*B[0][2];
    const double s2 = B[0][0]*B[1][3] - B[1][0]*B[0][3];
    const double s3 = B[0][1]*B[1][2] - B[1][1]*B[0][2];
    const double s4 = B[0][1]*B[1][3] - B[1][1]*B[0][3];
    const double s5 = B[0][2]*B[1][3] - B[1][2]*B[0][3];
    const double c5 = B[2][2]*B[3][3] - B[3][2]*B[2][3];
    const double c4 = B[2][1]*B[3][3] - B[3][1]*B[2][3];
    const double c3 = B[2][1]*B[3][2] - B[3][1]*B[2][2];
    const double c2 = B[2][0]*B[3][3] - B[3][0]*B[2][3];
    const double c1 = B[2][0]*B[3][2] - B[3][0]*B[2][2];
    const double c0 = B[2][0]*B[3][1] - B[3][0]*B[2][1];
    const double det = s0*c5 - s1*c4 + s2*c3 + s3*c2 - s4*c1 + s5*c0;
    const double id = 1.0 / det;
    I4[0][0] = ( B[1][1]*c5 - B[1][2]*c4 + B[1][3]*c3) * id;
    I4[0][1] = (-B[0][1]*c5 + B[0][2]*c4 - B[0][3]*c3) * id;
    I4[0][2] = ( B[3][1]*s5 - B[3][2]*s4 + B[3][3]*s3) * id;
    I4[0][3] = (-B[2][1]*s5 + B[2][2]*s4 - B[2][3]*s3) * id;
    I4[1][0] = (-B[1][0]*c5 + B[1][2]*c2 - B[1][3]*c1) * id;
    I4[1][1] = ( B[0][0]*c5 - B[0][2]*c2 + B[0][3]*c1) * id;
    I4[1][2] = (-B[3][0]*s5 + B[3][2]*s2 - B[3][3]*s1) * id;
    I4[1][3] = ( B[2][0]*s5 - B[2][2]*s2 + B[2][3]*s1) * id;
    I4[2][0] = ( B[1][0]*c4 - B[1][1]*c2 + B[1][3]*c0) * id;
    I4[2][1] = (-B[0][0]*c4 + B[0][1]*c2 - B[0][3]*c0) * id;
    I4[2][2] = ( B[3][0]*s4 - B[3][1]*s2 + B[3][3]*s0) * id;
    I4[2][3] = (-B[2][0]*s4 + B[2][1]*s2 - B[2][3]*s0) * id;
    I4[3][0] = (-B[1][0]*c3 + B[1][1]*c1 - B[1][2]*c0) * id;
    I4[3][1] = ( B[0][0]*c3 - B[0][1]*c1 + B[0][2]*c0) * id;
    I4[3][2] = (-B[3][0]*s3 + B[3][1]*s1 - B[3][2]*s0) * id;
    I4[3][3] = ( B[2][0]*s3 - B[2][1]*s1 + B[2][2]*s0) * id;
}

// Rank-4 update of 25 owned rows for TWO columns sharing each broadcast read.
#define PANEL_UPDATE2(H1, H2, WSG, BUF, BASE, SCL1, SCL2, M1, M2)             \
    {                                                                          \
        _Pragma("unroll")                                                      \
        for (int r = 0; r < kQrt; ++r) { H1[r] *= SCL1; H2[r] *= SCL2; }       \
        _Pragma("unroll")                                                      \
        for (int p = 0; p < kPan; ++p) {                                       \
            const double mp1 = M1[p], mp2 = M2[p];                             \
            _Pragma("unroll")                                                  \
            for (int c0 = 0; c0 < 2; ++c0) {                                   \
                const int off0 = c0 ? 13 : 0;                                  \
                const int cnt  = c0 ? 12 : 13;                                 \
                double w[13];                                                  \
                _Pragma("unroll")                                              \
                for (int u = 0; u < 13; ++u)                                   \
                    if (u < cnt) w[u] = WSG[BUF][p][BASE + off0 + u];          \
                __builtin_amdgcn_sched_barrier(0);                             \
                _Pragma("unroll")                                              \
                for (int u = 0; u < 13; ++u)                                   \
                    if (u < cnt) {                                             \
                        H1[off0+u] = fma(-mp1, w[u], H1[off0+u]);              \
                        H2[off0+u] = fma(-mp2, w[u], H2[off0+u]);              \
                    }                                                          \
            }                                                                  \
        }                                                                      \
    }

// -------------------------------------------------------------------------
// One block (256 thr = 4 waves) per (b,a): h=tid>>6 owns rows [h*25,h*25+25),
// lane=tid&63 owns columns j1=lane and j2=64+lane (j2<100 for lane<36).
// Each Wsg broadcast read feeds BOTH columns' FMAs -> half the LDS
// instructions per matrix vs 1-column layout (LDS-issue was the bottleneck).
__global__ __launch_bounds__(256) void ipm_invert_kernel(
    const double* __restrict__ K64, const int* __restrict__ labels,
    const double* __restrict__ z, const double* __restrict__ nu,
    const double* __restrict__ s, const double* __restrict__ lam,
    const double* __restrict__ mu_g,
    double* __restrict__ Hinv, double* __restrict__ tvec)
{
    const int b = blockIdx.x / kNW;
    const int a = blockIdx.x - b * kNW;
    const int tid = threadIdx.x;
    const int h = tid >> 6;            // row quarter 0..3
    const int lane = tid & 63;
    const int base = h * kQrt;
    const int j1 = lane;               // always < kNS
    const int j2 = 64 + lane;
    const bool a2 = (j2 < kNS);        // lane < 36
    const int js2 = a2 ? j2 : j1;

    __shared__ double za[kNS], sa[kNS], la[kNS], da[kNS], nus[kNS], r1s[kNS];
    __shared__ double part4[4][kNS];
    __shared__ alignas(16) double Wr [2][kPan][kNS + 8];  // raw panel rows
    __shared__ alignas(16) double Wsg[2][kPan][kNS + 8];  // signed panel rows
    __shared__ int labs[kNS];

    const double* zb = z   + (size_t)b * kNZ;
    const double* sb = s   + (size_t)b * kNZ;
    const double* lb = lam + (size_t)b * kNZ;
    const double* Kb = K64 + (size_t)b * kNS * kNS;

    if (tid < kNS) {
        double zv = zb[tid * kNW + a];
        double sv = sb[tid * kNW + a];
        double lv = lb[tid * kNW + a];
        za[tid] = zv; sa[tid] = sv; la[tid] = lv; da[tid] = lv / sv;
        nus[tid]  = nu[b * kNS + tid];
        labs[tid] = labels[b * kNS + tid];
    }
    __syncthreads();

    // Build both H columns in registers; fused partials of (K z_a).
    double h1[kQrt], h2[kQrt];
    double kz1 = 0.0, kz2 = 0.0;
    #pragma unroll
    for (int r = 0; r < kQrt; ++r) {
        const int i = base + r;
        double kv1 = Kb[(size_t)i * kNS + j1];
        double kv2 = Kb[(size_t)i * kNS + js2];
        kz1 += kv1 * za[i];
        kz2 += kv2 * za[i];
        h1[r] = (i == j1)  ? (kv1 + 1.0 + da[j1])  : kv1;
        h2[r] = (i == js2) ? (kv2 + 1.0 + da[js2]) : kv2;
    }
    part4[h][j1] = kz1;
    if (a2) part4[h][j2] = kz2;
    if (h == 0) {   // seed panel 0 rows (0..3); sign vs k0=0 -> all +
        #pragma unroll
        for (int p = 0; p < kPan; ++p) {
            Wr [0][p][j1] = h1[p];  Wsg[0][p][j1] = h1[p];
            if (a2) { Wr[0][p][j2] = h2[p]; Wsg[0][p][j2] = h2[p]; }
        }
    }
    __syncthreads();
    if (tid < kNS) {
        const double mu = mu_g[b];
        const int i = tid;
        double kz = part4[0][i] + part4[1][i] + part4[2][i] + part4[3][i];
        double yv = (labs[i] == a) ? 1.0 : 0.0;
        double rd = kz + za[i] - yv + la[i] + nus[i];
        double rp = za[i] + sa[i] - 0.1 * yv;      // h = C_REG*y
        double rc = la[i] * sa[i] - 0.1 * mu;      // sigma = 0.1
        r1s[i] = -rd + (rc - la[i] * rp) / sa[i];
    }

    // Panel-blocked Gauss-Jordan inverse: 25 panels, 1 barrier each.
    #pragma unroll 1
    for (int k0 = 0; k0 < kNS; k0 += kPan) {
        const int buf = (k0 >> 2) & 1, nbuf = 1 - buf;
        __syncthreads();                     // Wr/Wsg[buf] complete
        double B[4][4];
        #pragma unroll
        for (int p = 0; p < 4; ++p)
            #pragma unroll
            for (int q = 0; q < 4; ++q)
                B[p][q] = Wr[buf][p][k0 + q];
        double I4[4][4];
        adj4_inv(B, I4);

        const bool inp1 = (j1 >= k0) && (j1 < k0 + kPan);
        const bool inp2 = (js2 >= k0) && (js2 < k0 + kPan);
        double b1[4], b2[4];
        #pragma unroll
        for (int p = 0; p < 4; ++p) {
            b1[p] = inp1 ? ((j1  - k0 == p) ? 1.0 : 0.0) : Wr[buf][p][j1];
            b2[p] = inp2 ? ((js2 - k0 == p) ? 1.0 : 0.0) : Wr[buf][p][js2];
        }
        double m1[4], m2[4];
        #pragma unroll
        for (int p = 0; p < 4; ++p) {
            m1[p] = I4[p][0]*b1[0] + I4[p][1]*b1[1] + I4[p][2]*b1[2] + I4[p][3]*b1[3];
            m2[p] = I4[p][0]*b2[0] + I4[p][1]*b2[1] + I4[p][2]*b2[2] + I4[p][3]*b2[3];
        }
        const double scl1 = inp1 ? 0.0 : 1.0;
        const double scl2 = inp2 ? 0.0 : 1.0;
        PANEL_UPDATE2(h1, h2, Wsg, buf, base, scl1, scl2, m1, m2);

        // panel rows get m directly (overwrite generic update)
        if (k0 < base + kQrt && k0 + kPan - 1 >= base) {
            #pragma unroll
            for (int r = 0; r < kQrt; ++r) {
                const int i = base + r;
                if (i >= k0 && i < k0 + kPan) {
                    const int p = i - k0;
                    h1[r] = m1[p];
                    h2[r] = m2[p];
                }
            }
        }
        // write-ahead next panel rows (raw + signed vs kn0)
        const int kn0 = k0 + kPan;
        if (kn0 < kNS && kn0 < base + kQrt && kn0 + kPan - 1 >= base) {
            #pragma unroll
            for (int r = 0; r < kQrt; ++r) {
                const int i = base + r;
                if (i >= kn0 && i < kn0 + kPan) {
                    const int p = i - kn0;
                    Wr [nbuf][p][j1] = h1[r];
                    Wsg[nbuf][p][j1] = (j1 < kn0) ? -h1[r] : h1[r];
                    if (a2) {
                        Wr [nbuf][p][j2] = h2[r];
                        Wsg[nbuf][p][j2] = (j2 < kn0) ? -h2[r] : h2[r];
                    }
                }
            }
        }
    }

    // Write Hinv (coalesced) + t_a = Hinv * r1 (4-way combine via symmetry)
    double* Hb = Hinv + (size_t)(b * kNW + a) * kNS * kNS;
    double tp1 = 0.0, tp2 = 0.0;
    #pragma unroll
    for (int r = 0; r < kQrt; ++r) {
        const int i = base + r;
        Hb[(size_t)i * kNS + j1] = h1[r];
        tp1 += h1[r] * r1s[i];
        if (a2) Hb[(size_t)i * kNS + j2] = h2[r];
        tp2 += h2[r] * r1s[i];
    }
    part4[h][j1] = tp1;
    if (a2) part4[h][j2] = tp2;
    __syncthreads();
    if (tid < kNS)
        tvec[(size_t)(b * kNW + a) * kNS + tid] =
            part4[0][tid] + part4[1][tid] + part4[2][tid] + part4[3][tid];
}

// -------------------------------------------------------------------------
// S[b] = sum_a Hinv_a[b] — full-GPU streaming reduction (320 blocks).
__global__ __launch_bounds__(256) void sbuild_kernel(const double* __restrict__ Hinv,
                                                     double* __restrict__ Sg)
{
    const int b  = blockIdx.x / kNW;
    const int rc = blockIdx.x - b * kNW;
    const int tid = threadIdx.x;
    const double* Hb = Hinv + (size_t)b * kNW * kNS * kNS;
    for (int e = tid; e < kNS * kNS / kNW; e += 256) {
        const int idx = rc * (kNS * kNS / kNW) + e;
        double acc = 0.0;
        #pragma unroll
        for (int a = 0; a < kNW; ++a) acc += Hb[(size_t)a * kNS * kNS + idx];
        Sg[(size_t)b * kNS * kNS + idx] = acc;
    }
}

// -------------------------------------------------------------------------
// One block (256 thr) per b: panel-blocked GJ solve S dnu = sum_a t_a + rp2.
// Same 2-column layout; the rhs is column 100 = lane 36's j2 (never a pivot).
__global__ __launch_bounds__(256) void schur_solve_kernel(
    const double* __restrict__ Sg, const double* __restrict__ tvec,
    const double* __restrict__ z, double* __restrict__ dnu_g)
{
    const int b = blockIdx.x;
    const int tid = threadIdx.x;
    const int h = tid >> 6;
    const int lane = tid & 63;
    const int base = h * kQrt;
    const int j1 = lane;
    const int j2 = 64 + lane;
    const bool a2 = (j2 <= kNS);       // lane <= 36; j2==100 is the rhs column
    const int js2 = a2 ? j2 : j1;

    __shared__ double rhs[kNS];
    __shared__ alignas(16) double Wr [2][kPan][kNS + 8];
    __shared__ alignas(16) double Wsg[2][kPan][kNS + 8];

    const double* Sb = Sg   + (size_t)b * kNS * kNS;
    const double* tb = tvec + (size_t)b * kNW * kNS;
    const double* zb = z    + (size_t)b * kNZ;

    if (tid < kNS) {
        double acc = 0.0, rp2 = 0.0;
        #pragma unroll
        for (int a = 0; a < kNW; ++a) {
            acc += tb[a * kNS + tid];
            rp2 += zb[tid * kNW + a];
        }
        rhs[tid] = acc + rp2;
    }
    __syncthreads();

    double h1[kQrt], h2[kQrt];
    #pragma unroll
    for (int r = 0; r < kQrt; ++r) {
        const int i = base + r;
        h1[r] = Sb[(size_t)i * kNS + j1];
        h2[r] = (js2 == kNS) ? rhs[i]
              : Sb[(size_t)i * kNS + ((js2 < kNS) ? js2 : 0)];
    }
    if (h == 0) {
        #pragma unroll
        for (int p = 0; p < kPan; ++p) {
            Wr [0][p][j1] = h1[p];  Wsg[0][p][j1] = h1[p];
            if (a2) { Wr[0][p][j2] = h2[p]; Wsg[0][p][j2] = h2[p]; }
        }
    }

    #pragma unroll 1
    for (int k0 = 0; k0 < kNS; k0 += kPan) {
        const int buf = (k0 >> 2) & 1, nbuf = 1 - buf;
        __syncthreads();
        double B[4][4];
        #pragma unroll
        for (int p = 0; p < 4; ++p)
            #pragma unroll
            for (int q = 0; q < 4; ++q)
                B[p][q] = Wr[buf][p][k0 + q];
        double I4[4][4];
        adj4_inv(B, I4);

        const bool inp1 = (j1 >= k0) && (j1 < k0 + kPan);
        const bool inp2 = (js2 >= k0) && (js2 < k0 + kPan);   // never for j2==100
        double b1[4], b2[4];
        #pragma unroll
        for (int p = 0; p < 4; ++p) {
            b1[p] = inp1 ? ((j1  - k0 == p) ? 1.0 : 0.0) : Wr[buf][p][j1];
            b2[p] = inp2 ? ((js2 - k0 == p) ? 1.0 : 0.0) : Wr[buf][p][js2];
        }
        double m1[4], m2[4];
        #pragma unroll
        for (int p = 0; p < 4; ++p) {
            m1[p] = I4[p][0]*b1[0] + I4[p][1]*b1[1] + I4[p][2]*b1[2] + I4[p][3]*b1[3];
            m2[p] = I4[p][0]*b2[0] + I4[p][1]*b2[1] + I4[p][2]*b2[2] + I4[p][3]*b2[3];
        }
        const double scl1 = inp1 ? 0.0 : 1.0;
        const double scl2 = inp2 ? 0.0 : 1.0;
        PANEL_UPDATE2(h1, h2, Wsg, buf, base, scl1, scl2, m1, m2);

        if (k0 < base + kQrt && k0 + kPan - 1 >= base) {
            #pragma unroll
            for (int r = 0; r < kQrt; ++r) {
                const int i = base + r;
                if (i >= k0 && i < k0 + kPan) {
                    const int p = i - k0;
                    h1[r] = m1[p];
                    h2[r] = m2[p];
                }
            }
        }
        const int kn0 = k0 + kPan;
        if (kn0 < kNS && kn0 < base + kQrt && kn0 + kPan - 1 >= base) {
            #pragma unroll
            for (int r = 0; r < kQrt; ++r) {
                const int i = base + r;
                if (i >= kn0 && i < kn0 + kPan) {
                    const int p = i - kn0;
                    Wr [nbuf][p][j1] = h1[r];
                    Wsg[nbuf][p][j1] = (j1 < kn0) ? -h1[r] : h1[r];
                    if (a2) {
                        Wr [nbuf][p][j2] = h2[r];
                        Wsg[nbuf][p][j2] = (j2 < kn0) ? -h2[r] : h2[r];
                    }
                }
            }
        }
    }

    if (j2 == kNS) {   // lane 36: rhs column now holds dnu for owned rows
        #pragma unroll
        for (int r = 0; r < kQrt; ++r)
            dnu_g[(size_t)b * kNS + base + r] = h2[r];
    }
}

// -------------------------------------------------------------------------
// One block per (b,a): dz_a = t_a - Hinv_a*dnu (full-GPU streaming of Hinv),
// ds/dlam, per-block min step-ratio.
__global__ __launch_bounds__(256) void dz_kernel(
    const int* __restrict__ labels,
    const double* __restrict__ Hinv, const double* __restrict__ tvec,
    const double* __restrict__ dnu_g,
    const double* __restrict__ z, const double* __restrict__ s,
    const double* __restrict__ lam, const double* __restrict__ mu_g,
    double* __restrict__ dz_g, double* __restrict__ ds_g,
    double* __restrict__ dl_g, double* __restrict__ minr_g)
{
    const int b = blockIdx.x / kNW;
    const int a = blockIdx.x - b * kNW;
    const int tid = threadIdx.x;
    const int h = tid >> 7;
    const int j = tid & 127;

    __shared__ double dnus[kNS];
    __shared__ double p2[2][kNS];
    __shared__ double red[256];

    const double* Hb = Hinv + (size_t)(b * kNW + a) * kNS * kNS;

    if (tid < kNS) dnus[tid] = dnu_g[(size_t)b * kNS + tid];
    __syncthreads();

    if (j < kNS) {
        double p = 0.0;
        #pragma unroll
        for (int r = 0; r < kHalf; ++r)
            p += Hb[(size_t)(h * kHalf + r) * kNS + j] * dnus[h * kHalf + r];
        p2[h][j] = p;
    }
    __syncthreads();

    double lmin = 1e300;
    if (tid < kNS) {
        const int i = tid;
        const size_t m = (size_t)b * kNZ + i * kNW + a;
        const double mu = mu_g[b];
        double dz = tvec[(size_t)(b * kNW + a) * kNS + i] - (p2[0][i] + p2[1][i]);
        double yv = (labels[b * kNS + i] == a) ? 1.0 : 0.0;
        double zv = z[m], sv = s[m], lv = lam[m];
        double rp = zv + sv - 0.1 * yv;
        double rc = lv * sv - 0.1 * mu;
        double ds = -rp - dz;
        double dl = (-rc - lv * ds) / sv;
        dz_g[m] = dz; ds_g[m] = ds; dl_g[m] = dl;
        if (ds < 0.0) lmin = fmin(lmin, -sv / ds);
        if (dl < 0.0) lmin = fmin(lmin, -lv / dl);
    }
    red[tid] = lmin; __syncthreads();
    for (int off = 128; off > 0; off >>= 1) {
        if (tid < off) red[tid] = fmin(red[tid], red[tid + off]);
        __syncthreads();
    }
    if (tid == 0) minr_g[b * kNW + a] = red[0];
}

// -------------------------------------------------------------------------
// One block per b: alpha from the 10 per-class mins, state update, next mu.
__global__ __launch_bounds__(256) void update_kernel(
    const double* __restrict__ minr_g, const double* __restrict__ dnu_g,
    const double* __restrict__ dz_g, const double* __restrict__ ds_g,
    const double* __restrict__ dl_g,
    double* __restrict__ z, double* __restrict__ nu,
    double* __restrict__ s, double* __restrict__ lam,
    double* __restrict__ mu_g)
{
    const int b = blockIdx.x;
    const int tid = threadIdx.x;
    __shared__ double red[256];

    double am = 1e300;
    #pragma unroll
    for (int a = 0; a < kNW; ++a) am = fmin(am, minr_g[b * kNW + a]);
    const double alpha = fmin(1.0, 0.99 * am);

    double* zb = z   + (size_t)b * kNZ;
    double* sb = s   + (size_t)b * kNZ;
    double* lb = lam + (size_t)b * kNZ;

    double md = 0.0;
    #pragma unroll
    for (int tcl = 0; tcl < 4; ++tcl) {
        const int  e = tid + tcl * 256;
        const size_t m = (size_t)b * kNZ + e;
        if (e < kNZ) {
            double zn = zb[e] + alpha * dz_g[m];
            double sn = sb[e] + alpha * ds_g[m];
            double ln = lb[e] + alpha * dl_g[m];
            zb[e] = zn; sb[e] = sn; lb[e] = ln;
            md += sn * ln;
        }
    }
    red[tid] = md; __syncthreads();
    for (int off = 128; off > 0; off >>= 1) {
        if (tid < off) red[tid] += red[tid + off];
        __syncthreads();
    }
    if (tid == 0) mu_g[b] = red[0] / kNZ;
    if (tid < kNS) nu[(size_t)b * kNS + tid] += alpha * dnu_g[(size_t)b * kNS + tid];
}

// -------------------------------------------------------------------------
// logits[b][q][n] = sum_s compat[b][s][q] * z[b][s*10+n]
__global__ __launch_bounds__(256) void logits_kernel(const float* __restrict__ compat,
                                                     const double* __restrict__ z,
                                                     float* __restrict__ out)
{
    const int b = blockIdx.x;
    const int tid = threadIdx.x;
    const float* cb = compat + (size_t)b * kNS * kNQ;
    const double* zb = z + (size_t)b * kNZ;
    __shared__ double zs[kNZ];
    for (int m = tid; m < kNZ; m += 256) zs[m] = zb[m];
    __syncthreads();
    for (int idx = tid; idx < kNQ * kNW; idx += 256) {
        int q = idx / kNW, n = idx - q * kNW;
        double acc = 0.0;
        for (int s2 = 0; s2 < kNS; ++s2)
            acc += (double)cb[(size_t)s2 * kNQ + q] * zs[s2 * kNW + n];
        out[(size_t)b * kNQ * kNW + idx] = (float)acc;
    }
}

// -------------------------------------------------------------------------
extern "C" void kernel_launch(void* const* d_in, const int* in_sizes, int n_in,
                              void* d_out, int out_size, void* d_ws, size_t ws_size,
                              hipStream_t stream)
{
    const float* sup    = (const float*)d_in[0];   // (32,10,10,512)
    const int*   labels = (const int*)  d_in[1];   // (32,10,10)
    const float* qry    = (const float*)d_in[2];   // (32,10,15,512)
    float* out = (float*)d_out;                    // (32,150,10) fp32

    char* ws = (char*)d_ws;
    size_t off = 0;
    auto alloc = [&](size_t bytes) -> void* {
        void* p = ws + off;
        off += (bytes + 255) & ~(size_t)255;
        return p;
    };
    double* K64    = (double*)alloc(sizeof(double) * kB * kNS * kNS);        // 2.56 MB
    double* z      = (double*)alloc(sizeof(double) * kB * kNZ);
    double* nu     = (double*)alloc(sizeof(double) * kB * kNS);
    double* s      = (double*)alloc(sizeof(double) * kB * kNZ);
    double* lam    = (double*)alloc(sizeof(double) * kB * kNZ);
    double* mu_g   = (double*)alloc(sizeof(double) * kB);
    double* Hinv   = (double*)alloc(sizeof(double) * kB * kNW * kNS * kNS);  // 25.6 MB
    double* Sg     = (double*)alloc(sizeof(double) * kB * kNS * kNS);        // 2.56 MB
    double* tvec   = (double*)alloc(sizeof(double) * kB * kNW * kNS);
    double* dnu_g  = (double*)alloc(sizeof(double) * kB * kNS);
    double* dz_g   = (double*)alloc(sizeof(double) * kB * kNZ);
    double* ds_g   = (double*)alloc(sizeof(double) * kB * kNZ);
    double* dl_g   = (double*)alloc(sizeof(double) * kB * kNZ);
    double* minr_g = (double*)alloc(sizeof(double) * kB * kNW);
    float*  compat = (float*) alloc(sizeof(float)  * kB * kNS * kNQ);        // 1.92 MB

    gram_kernel  <<<dim3(kNS, kB), 128, 0, stream>>>(sup, K64);
    compat_kernel<<<dim3(kNS, kB), 256, 0, stream>>>(sup, qry, compat);
    init_kernel  <<<kB, 256, 0, stream>>>(z, nu, s, lam, mu_g);

    for (int it = 0; it < kIt; ++it) {
        ipm_invert_kernel<<<kB * kNW, 256, 0, stream>>>(K64, labels, z, nu, s,
                                                        lam, mu_g, Hinv, tvec);
        sbuild_kernel<<<kB * kNW, 256, 0, stream>>>(Hinv, Sg);
        schur_solve_kernel<<<kB, 256, 0, stream>>>(Sg, tvec, z, dnu_g);
        dz_kernel<<<kB * kNW, 256, 0, stream>>>(labels, Hinv, tvec, dnu_g,
                                                z, s, lam, mu_g,
                                                dz_g, ds_g, dl_g, minr_g);
        update_kernel<<<kB, 256, 0, stream>>>(minr_g, dnu_g, dz_g, ds_g, dl_g,
                                              z, nu, s, lam, mu_g);
    }

    logits_kernel<<<kB, 256, 0, stream>>>(compat, z, out);
}